// Round 2
// baseline (7487.223 us; speedup 1.0000x reference)
//
#include <hip/hip_runtime.h>
#include <hip/hip_bf16.h>

#define KW 5
#define NSW 2
#define EPS 1e-5f

// ---- exact transliteration of reference window/bias start functions ----
__device__ __forceinline__ int win_start(int i, int L, int d){
  if (d <= 1){
    int s = i - NSW; if (s < 0) s = 0;
    if (i + NSW >= L) s += L - i - NSW - 1;
    return s;
  }
  int ni = i - NSW*d;
  if (ni < 0) return i % d;
  if (i + NSW*d >= L){
    int imodd = i % d;
    int a = (L / d) * d;
    int b = L - a;
    if (imodd < b) return L - b + imodd - 2*NSW*d;
    return a + imodd - KW*d;
  }
  return ni;
}
__device__ __forceinline__ int pb_start(int i, int L, int d){
  if (d <= 1){
    int s = NSW;
    if (i < NSW) s += NSW - i;
    if (i + NSW >= L) s += L - i - 1 - NSW;
    return s;
  }
  if (i - NSW*d < 0) return KW - 1 - i/d;
  if (i + NSW*d >= L) return (L - i - 1)/d;
  return NSW;
}

// ---- NCHW -> NHWC (f32) ----
__global__ __launch_bounds__(256)
void k_nchw2nhwc(const float* __restrict__ in, float* __restrict__ out,
                 int H, int W){
  int t = blockIdx.x; int c = threadIdx.x;
  int x = t % W; int y = (t / W) % H; int b = t / (W*H);
  out[(size_t)t*256 + c] = in[(((size_t)b*256 + c)*H + y)*W + x];
}

// ---- LayerNorm over channel dim (C=256), one block per token ----
__global__ __launch_bounds__(256)
void k_ln(const float* __restrict__ x, const float* __restrict__ w,
          const float* __restrict__ b, float* __restrict__ out)
{
  __shared__ float red[4];
  __shared__ float stats[2];
  int t = blockIdx.x, c = threadIdx.x;
  float v = x[(size_t)t*256 + c];
  float s = v;
  #pragma unroll
  for (int m = 32; m >= 1; m >>= 1) s += __shfl_xor(s, m, 64);
  int wave = c >> 6;
  if ((c & 63) == 0) red[wave] = s;
  __syncthreads();
  if (c == 0) stats[0] = (red[0]+red[1]+red[2]+red[3]) * (1.f/256.f);
  __syncthreads();
  float mean = stats[0];
  float dd = v - mean;
  float s2 = dd*dd;
  #pragma unroll
  for (int m = 32; m >= 1; m >>= 1) s2 += __shfl_xor(s2, m, 64);
  if ((c & 63) == 0) red[wave] = s2;
  __syncthreads();
  if (c == 0) stats[1] = (red[0]+red[1]+red[2]+red[3]) * (1.f/256.f);
  __syncthreads();
  float var = stats[1];
  out[(size_t)t*256 + c] = dd * rsqrtf(var + EPS) * w[c] + b[c];
}

// ---- generic tiled GEMM: C[t,n] = epi(A[t,:].W[n,:] + bias[n]) ----
// A: T x Kd (f32), W: N x Kd (f32, row-major), bias: N
// epi: 0 none, 1 qkv (scale cols<256), 2 gelu, 3 residual+gate (N==256)
#define BM 64
#define BN 64
#define BK 16
__global__ __launch_bounds__(256)
void k_gemm(const float* __restrict__ A, const float* __restrict__ W,
            const float* __restrict__ bias, float* __restrict__ C,
            int T, int N, int Kd, int epi,
            const float* __restrict__ res, const float* __restrict__ gate)
{
  __shared__ float As[BK][BM+4];
  __shared__ float Ws[BK][BN+4];
  int tile_n = blockIdx.x * BN;
  int tile_t = blockIdx.y * BM;
  int tid = threadIdx.x;
  int ty = tid >> 4, tx = tid & 15;
  float acc[4][4] = {};
  for (int k0 = 0; k0 < Kd; k0 += BK){
    #pragma unroll
    for (int i = 0; i < 4; i++){
      int idx = tid + i*256;
      int row = idx >> 4, col = idx & 15;
      int t = tile_t + row;
      As[col][row] = (t < T) ? A[(size_t)t*Kd + k0 + col] : 0.f;
    }
    #pragma unroll
    for (int i = 0; i < 4; i++){
      int idx = tid + i*256;
      int n = idx >> 4, k = idx & 15;
      int gn = tile_n + n;
      Ws[k][n] = (gn < N) ? W[(size_t)gn*Kd + k0 + k] : 0.f;
    }
    __syncthreads();
    #pragma unroll
    for (int kk = 0; kk < BK; kk++){
      float a[4], w[4];
      #pragma unroll
      for (int i = 0; i < 4; i++) a[i] = As[kk][ty*4 + i];
      #pragma unroll
      for (int j = 0; j < 4; j++) w[j] = Ws[kk][tx*4 + j];
      #pragma unroll
      for (int i = 0; i < 4; i++)
        #pragma unroll
        for (int j = 0; j < 4; j++) acc[i][j] += a[i]*w[j];
    }
    __syncthreads();
  }
  #pragma unroll
  for (int i = 0; i < 4; i++){
    int t = tile_t + ty*4 + i;
    if (t >= T) continue;
    #pragma unroll
    for (int j = 0; j < 4; j++){
      int n = tile_n + tx*4 + j;
      if (n >= N) continue;
      float v = acc[i][j] + bias[n];
      if (epi == 1){ if (n < 256) v *= 0.17677669529663689f; }
      else if (epi == 2){ v = 0.5f*v*(1.f + erff(v*0.70710678118654752f)); }
      else if (epi == 3){ v = res[(size_t)t*(size_t)N + n] + gate[n] * v; }
      C[(size_t)t*(size_t)N + n] = v;
    }
  }
}

// ---- neighborhood attention: one block per token; 8 heads x 32 lanes ----
__global__ __launch_bounds__(256)
void k_attn(const float* __restrict__ qkv, const float* __restrict__ rpb,
            float* __restrict__ o, int Hh, int Ww, int d)
{
  int t = blockIdx.x;
  int j = t % Ww; int i = (t / Ww) % Hh;
  int base = (t / (Ww*Hh)) * Hh * Ww;
  int head = threadIdx.x >> 5;
  int c = threadIdx.x & 31;
  float q = qkv[(size_t)t*768 + head*32 + c];  // already scaled in epilogue
  int is = win_start(i, Hh, d), js = win_start(j, Ww, d);
  int bi = pb_start(i, Hh, d), bj = pb_start(j, Ww, d);
  float logits[25];
  int tns[25];
  #pragma unroll
  for (int x = 0; x < 5; x++){
    int ii = is + x*d;
    #pragma unroll
    for (int y = 0; y < 5; y++){
      int jj = js + y*d;
      int tn = base + ii*Ww + jj;
      tns[x*5+y] = tn;
      float kv = qkv[(size_t)tn*768 + 256 + head*32 + c];
      float p = q * kv;
      #pragma unroll
      for (int m = 16; m >= 1; m >>= 1) p += __shfl_xor(p, m, 32);
      p += rpb[head*81 + (bi + x)*9 + (bj + y)];
      logits[x*5+y] = p;
    }
  }
  float mx = logits[0];
  #pragma unroll
  for (int p = 1; p < 25; p++) mx = fmaxf(mx, logits[p]);
  float ssum = 0.f;
  #pragma unroll
  for (int p = 0; p < 25; p++){ float e = expf(logits[p] - mx); logits[p] = e; ssum += e; }
  float inv = 1.f / ssum;
  float acc = 0.f;
  #pragma unroll
  for (int p = 0; p < 25; p++)
    acc += logits[p] * qkv[(size_t)tns[p]*768 + 512 + head*32 + c];
  o[(size_t)t*256 + head*32 + c] = acc * inv;
}

// ---- bilinear upsample (align-corners), NHWC f32 -> NHWC f32 ----
__global__ __launch_bounds__(256)
void k_upsample(const float* __restrict__ in, float* __restrict__ out,
                int h, int w, int H2, int W2)
{
  int t = blockIdx.x; int c = threadIdx.x;
  int x = t % W2; int y = (t / W2) % H2; int b = t / (W2*H2);
  float fy = (float)y * (float)(h-1) / (float)(H2-1);
  float fx = (float)x * (float)(w-1) / (float)(W2-1);
  int y0 = (int)floorf(fy); int y1 = min(y0+1, h-1); float wy = fy - (float)y0;
  int x0 = (int)floorf(fx); int x1 = min(x0+1, w-1); float wx = fx - (float)x0;
  const float* basep = in + (size_t)b*h*w*256;
  float a  = basep[((size_t)y0*w + x0)*256 + c];
  float bb = basep[((size_t)y0*w + x1)*256 + c];
  float cc = basep[((size_t)y1*w + x0)*256 + c];
  float e  = basep[((size_t)y1*w + x1)*256 + c];
  out[(size_t)t*256 + c] = a*(1.f-wy)*(1.f-wx) + bb*(1.f-wy)*wx
                         + cc*wy*(1.f-wx) + e*wy*wx;
}

// ---- fuse: 1x1 conv over cat([feat(NCHW), up(NHWC)]) + BN ----
__global__ __launch_bounds__(256)
void k_fuse(const float* __restrict__ feat, const float* __restrict__ up,
            const float* __restrict__ fw, const float* __restrict__ fb,
            const float* __restrict__ bw, const float* __restrict__ bb,
            const float* __restrict__ bm, const float* __restrict__ bv,
            float* __restrict__ xout, int Hh, int Ww)
{
  __shared__ float cat[512];
  int t = blockIdx.x; int o = threadIdx.x;
  int x = t % Ww; int y = (t / Ww) % Hh; int b = t / (Ww*Hh);
  cat[o]       = feat[(((size_t)b*256 + o)*Hh + y)*Ww + x];
  cat[256 + o] = up[(size_t)t*256 + o];
  __syncthreads();
  const float* wrow = fw + (size_t)o*512;
  float acc = 0.f;
  for (int cidx = 0; cidx < 512; cidx++) acc += cat[cidx]*wrow[cidx];
  acc += fb[o];
  float s = bw[o] * rsqrtf(bv[o] + EPS);
  xout[(size_t)t*256 + o] = (acc - bm[o])*s + bb[o];
}

// ---- 3x3 conv (SAME) + BN + ReLU, NHWC f32 in -> NHWC f32 out (Cout=256) ----
__global__ __launch_bounds__(256)
void k_conv1(const float* __restrict__ in, const float* __restrict__ wgt,
             const float* __restrict__ bias, const float* __restrict__ bnw,
             const float* __restrict__ bnb, const float* __restrict__ bnm,
             const float* __restrict__ bnv, float* __restrict__ out,
             int H, int W)
{
  __shared__ float patch[2304];
  int t = blockIdx.x; int o = threadIdx.x;
  int x = t % W; int y = (t / W) % H; int b = t / (W*H);
  for (int idx = o; idx < 2304; idx += 256){
    int c = idx & 255; int tap = idx >> 8;
    int ky = tap/3 - 1, kx = tap%3 - 1;
    int yy = y + ky, xx = x + kx;
    patch[idx] = (yy >= 0 && yy < H && xx >= 0 && xx < W)
               ? in[(((size_t)b*H + yy)*W + xx)*256 + c] : 0.f;
  }
  __syncthreads();
  const float* wo = wgt + (size_t)o*2304;
  float acc = 0.f;
  for (int c = 0; c < 256; c++){
    #pragma unroll
    for (int tap = 0; tap < 9; tap++)
      acc += patch[tap*256 + c] * wo[c*9 + tap];
  }
  acc += bias[o];
  float s = bnw[o] * rsqrtf(bnv[o] + EPS);
  float v = (acc - bnm[o])*s + bnb[o];
  out[(size_t)t*256 + o] = fmaxf(v, 0.f);
}

// ---- final 3x3 conv + BN + ReLU, NHWC f32 in -> NCHW f32 out (Cout=17) ----
__global__ __launch_bounds__(256)
void k_conv2(const float* __restrict__ in, const float* __restrict__ wgt,
             const float* __restrict__ bias, const float* __restrict__ bnw,
             const float* __restrict__ bnb, const float* __restrict__ bnm,
             const float* __restrict__ bnv, float* __restrict__ out,
             int H, int W)
{
  __shared__ float patch[2304];
  int t = blockIdx.x; int o = threadIdx.x;
  int x = t % W; int y = (t / W) % H; int b = t / (W*H);
  for (int idx = o; idx < 2304; idx += 256){
    int c = idx & 255; int tap = idx >> 8;
    int ky = tap/3 - 1, kx = tap%3 - 1;
    int yy = y + ky, xx = x + kx;
    patch[idx] = (yy >= 0 && yy < H && xx >= 0 && xx < W)
               ? in[(((size_t)b*H + yy)*W + xx)*256 + c] : 0.f;
  }
  __syncthreads();
  if (o < 17){
    const float* wo = wgt + (size_t)o*2304;
    float acc = 0.f;
    for (int c = 0; c < 256; c++){
      #pragma unroll
      for (int tap = 0; tap < 9; tap++)
        acc += patch[tap*256 + c] * wo[c*9 + tap];
    }
    acc += bias[o];
    float s = bnw[o] * rsqrtf(bnv[o] + EPS);
    float v = (acc - bnm[o])*s + bnb[o];
    out[(((size_t)b*17 + o)*H + y)*W + x] = fmaxf(v, 0.f);
  }
}

extern "C" void kernel_launch(void* const* d_in, const int* in_sizes, int n_in,
                              void* d_out, int out_size, void* d_ws, size_t ws_size,
                              hipStream_t stream)
{
  (void)in_sizes; (void)n_in; (void)out_size; (void)ws_size;
  const float* x0     = (const float*)d_in[0];
  const float* x1     = (const float*)d_in[1];
  const float* x2     = (const float*)d_in[2];
  const float* x3     = (const float*)d_in[3];
  const float* ln1_w  = (const float*)d_in[4];
  const float* ln1_b  = (const float*)d_in[5];
  const float* qkv_w  = (const float*)d_in[6];
  const float* qkv_b  = (const float*)d_in[7];
  const float* rpb    = (const float*)d_in[8];
  const float* proj_w = (const float*)d_in[9];
  const float* proj_b = (const float*)d_in[10];
  const float* ln2_w  = (const float*)d_in[11];
  const float* ln2_b  = (const float*)d_in[12];
  const float* fc1_w  = (const float*)d_in[13];
  const float* fc1_b  = (const float*)d_in[14];
  const float* fc2_w  = (const float*)d_in[15];
  const float* fc2_b  = (const float*)d_in[16];
  const float* g1     = (const float*)d_in[17];
  const float* g2     = (const float*)d_in[18];
  const float* fuse_w = (const float*)d_in[19];
  const float* fuse_b = (const float*)d_in[20];
  const float* fbn_w  = (const float*)d_in[21];
  const float* fbn_b  = (const float*)d_in[22];
  const float* fbn_m  = (const float*)d_in[23];
  const float* fbn_v  = (const float*)d_in[24];
  const float* lc1_w  = (const float*)d_in[25];
  const float* lc1_b  = (const float*)d_in[26];
  const float* lbn1_w = (const float*)d_in[27];
  const float* lbn1_b = (const float*)d_in[28];
  const float* lbn1_m = (const float*)d_in[29];
  const float* lbn1_v = (const float*)d_in[30];
  const float* lc2_w  = (const float*)d_in[31];
  const float* lc2_b  = (const float*)d_in[32];
  const float* lbn2_w = (const float*)d_in[33];
  const float* lbn2_b = (const float*)d_in[34];
  const float* lbn2_m = (const float*)d_in[35];
  const float* lbn2_v = (const float*)d_in[36];

  // workspace layout (f32): X: 3145728, Hb: 3145728 (also attn-out), Qb: 12582912
  float* X  = (float*)d_ws;
  float* Hb = X  + 3145728;
  float* Qb = Hb + 3145728;

  auto gemm = [&](const float* A, const float* W, const float* bias, float* C,
                  int T, int N, int Kd, int epi, const float* res, const float* gate){
    dim3 g(N/BN, (T + BM - 1)/BM);
    k_gemm<<<g, 256, 0, stream>>>(A, W, bias, C, T, N, Kd, epi, res, gate);
  };

  auto nat = [&](int l, int d, int Hh, int Ww){
    int T = 4*Hh*Ww;
    k_ln<<<T, 256, 0, stream>>>(X, ln1_w + l*256, ln1_b + l*256, Hb);
    gemm(Hb, qkv_w + (size_t)l*196608, qkv_b + l*768, Qb, T, 768, 256, 1, nullptr, nullptr);
    k_attn<<<T, 256, 0, stream>>>(Qb, rpb + l*648, Hb, Hh, Ww, d);  // Hb reused as attn-out
    gemm(Hb, proj_w + (size_t)l*65536, proj_b + l*256, X, T, 256, 256, 3, X, g1 + l*256);
    k_ln<<<T, 256, 0, stream>>>(X, ln2_w + l*256, ln2_b + l*256, Hb);
    gemm(Hb, fc1_w + (size_t)l*262144, fc1_b + l*1024, Qb, T, 1024, 256, 2, nullptr, nullptr);
    gemm(Qb, fc2_w + (size_t)l*262144, fc2_b + l*256, X, T, 256, 1024, 3, X, g2 + l*256);
  };

  // level 3: 8x6
  k_nchw2nhwc<<<4*8*6, 256, 0, stream>>>(x3, X, 8, 6);
  nat(0, 1, 8, 6);
  nat(1, 1, 8, 6);
  k_upsample<<<4*16*12, 256, 0, stream>>>(X, Hb, 8, 6, 16, 12);
  k_fuse<<<4*16*12, 256, 0, stream>>>(x2, Hb, fuse_w, fuse_b, fbn_w, fbn_b,
                                      fbn_m, fbn_v, X, 16, 12);
  // level 2: 16x12
  nat(2, 2, 16, 12);
  nat(3, 2, 16, 12);
  k_upsample<<<4*32*24, 256, 0, stream>>>(X, Hb, 16, 12, 32, 24);
  k_fuse<<<4*32*24, 256, 0, stream>>>(x1, Hb, fuse_w + 131072, fuse_b + 256,
                                      fbn_w + 256, fbn_b + 256, fbn_m + 256,
                                      fbn_v + 256, X, 32, 24);
  // level 1: 32x24
  nat(4, 4, 32, 24);
  nat(5, 4, 32, 24);
  k_upsample<<<4*64*48, 256, 0, stream>>>(X, Hb, 32, 24, 64, 48);
  k_fuse<<<4*64*48, 256, 0, stream>>>(x0, Hb, fuse_w + 262144, fuse_b + 512,
                                      fbn_w + 512, fbn_b + 512, fbn_m + 512,
                                      fbn_v + 512, X, 64, 48);
  // level 0: 64x48
  nat(6, 8, 64, 48);
  nat(7, 8, 64, 48);
  // final convs
  k_conv1<<<4*64*48, 256, 0, stream>>>(X, lc1_w, lc1_b, lbn1_w, lbn1_b,
                                       lbn1_m, lbn1_v, Hb, 64, 48);
  k_conv2<<<4*64*48, 256, 0, stream>>>(Hb, lc2_w, lc2_b, lbn2_w, lbn2_b,
                                       lbn2_m, lbn2_v, (float*)d_out, 64, 48);
}

// Round 3
// 1806.042 us; speedup vs baseline: 4.1457x; 4.1457x over previous
//
#include <hip/hip_runtime.h>
#include <hip/hip_bf16.h>

typedef __hip_bfloat16 bft;
typedef short bf8s __attribute__((ext_vector_type(8)));   // 8 bf16 (4 VGPRs)
typedef float f4 __attribute__((ext_vector_type(4)));

#define KW 5
#define NSW 2
#define EPS 1e-5f

__device__ __forceinline__ int win_start(int i, int L, int d){
  if (d <= 1){
    int s = i - NSW; if (s < 0) s = 0;
    if (i + NSW >= L) s += L - i - NSW - 1;
    return s;
  }
  int ni = i - NSW*d;
  if (ni < 0) return i % d;
  if (i + NSW*d >= L){
    int imodd = i % d;
    int a = (L / d) * d;
    int b = L - a;
    if (imodd < b) return L - b + imodd - 2*NSW*d;
    return a + imodd - KW*d;
  }
  return ni;
}
__device__ __forceinline__ int pb_start(int i, int L, int d){
  if (d <= 1){
    int s = NSW;
    if (i < NSW) s += NSW - i;
    if (i + NSW >= L) s += L - i - 1 - NSW;
    return s;
  }
  if (i - NSW*d < 0) return KW - 1 - i/d;
  if (i + NSW*d >= L) return (L - i - 1)/d;
  return NSW;
}

// ---- fp32 -> bf16 convert, up to 4 source segments, one launch ----
__global__ __launch_bounds__(256)
void k_cvt4(const float* __restrict__ s0, int n0, const float* __restrict__ s1, int n1,
            const float* __restrict__ s2, int n2, const float* __restrict__ s3, int n3,
            bft* __restrict__ dst)
{
  int total = n0 + n1 + n2 + n3;
  for (int i = blockIdx.x*256 + threadIdx.x; i < total; i += gridDim.x*256){
    float v;
    int j = i;
    if (j < n0) v = s0[j];
    else { j -= n0;
      if (j < n1) v = s1[j];
      else { j -= n1;
        if (j < n2) v = s2[j];
        else v = s3[j - n2];
      }
    }
    dst[i] = __float2bfloat16(v);
  }
}

// ---- conv weight repack: OIHW fp32 -> [o][tap*256+c] bf16 (o padded) ----
__global__ __launch_bounds__(256)
void k_repack(const float* __restrict__ in, bft* __restrict__ out, int O_in)
{
  int o = blockIdx.x, c = threadIdx.x;
  #pragma unroll
  for (int tap = 0; tap < 9; tap++){
    float v = (o < O_in) ? in[((size_t)(o*256 + c))*9 + tap] : 0.f;
    out[(size_t)o*2304 + tap*256 + c] = __float2bfloat16(v);
  }
}

// ---- NCHW -> NHWC (f32) ----
__global__ __launch_bounds__(256)
void k_nchw2nhwc(const float* __restrict__ in, float* __restrict__ out,
                 int H, int W){
  int t = blockIdx.x; int c = threadIdx.x;
  int x = t % W; int y = (t / W) % H; int b = t / (W*H);
  out[(size_t)t*256 + c] = in[(((size_t)b*256 + c)*H + y)*W + x];
}

// ---- LayerNorm (C=256), one block per token; fp32 in, bf16 out ----
__global__ __launch_bounds__(256)
void k_ln(const float* __restrict__ x, const float* __restrict__ w,
          const float* __restrict__ b, bft* __restrict__ out)
{
  __shared__ float red[4];
  __shared__ float stats[2];
  int t = blockIdx.x, c = threadIdx.x;
  float v = x[(size_t)t*256 + c];
  float s = v;
  #pragma unroll
  for (int m = 32; m >= 1; m >>= 1) s += __shfl_xor(s, m, 64);
  int wave = c >> 6;
  if ((c & 63) == 0) red[wave] = s;
  __syncthreads();
  if (c == 0) stats[0] = (red[0]+red[1]+red[2]+red[3]) * (1.f/256.f);
  __syncthreads();
  float mean = stats[0];
  float dd = v - mean;
  float s2 = dd*dd;
  #pragma unroll
  for (int m = 32; m >= 1; m >>= 1) s2 += __shfl_xor(s2, m, 64);
  if ((c & 63) == 0) red[wave] = s2;
  __syncthreads();
  if (c == 0) stats[1] = (red[0]+red[1]+red[2]+red[3]) * (1.f/256.f);
  __syncthreads();
  float var = stats[1];
  out[(size_t)t*256 + c] = __float2bfloat16(dd * rsqrtf(var + EPS) * w[c] + b[c]);
}

// ---- MFMA bf16 GEMM: C[m,n] = epi( sum_k A[m,k]*W[n,k] + bias[n] ) ----
// A: Mloc x K bf16 row-major; W: N x K bf16 row-major. 64x64 tile, 4 waves.
// epi: 1 qkv-scale(n<256)->bf16; 2 gelu->bf16; 3 res+gate->f32;
//      4 fuse-BN->f32; 5 conv-BN+ReLU->bf16; 6 conv-BN+ReLU->f32 NCHW (n<Npost)
__global__ __launch_bounds__(256)
void k_gemm(const bft* __restrict__ A, const bft* __restrict__ W,
            const float* __restrict__ bias, void* __restrict__ Cv,
            int N, int K, int epi, int t0, int Npost,
            const float* __restrict__ res, const float* __restrict__ gate,
            const float* __restrict__ bn_w, const float* __restrict__ bn_b,
            const float* __restrict__ bn_m, const float* __restrict__ bn_v,
            int HH, int WW)
{
  int tile_n = blockIdx.x * 64;
  int tile_m = blockIdx.y * 64;
  int tid = threadIdx.x;
  int wv   = tid >> 6;
  int lane = tid & 63;
  int q    = lane >> 4;
  int l15  = lane & 15;

  const bft* Arow  = A + (size_t)(tile_m + wv*16 + l15) * K + q*8;
  const bft* Wrow  = W + (size_t)(tile_n + l15) * K + q*8;

  f4 acc0 = {0.f,0.f,0.f,0.f};
  f4 acc1 = acc0, acc2 = acc0, acc3 = acc0;

  for (int k0 = 0; k0 < K; k0 += 32){
    bf8s a  = *(const bf8s*)(Arow + k0);
    bf8s b0 = *(const bf8s*)(Wrow + k0);
    bf8s b1 = *(const bf8s*)(Wrow + (size_t)16*K + k0);
    bf8s b2 = *(const bf8s*)(Wrow + (size_t)32*K + k0);
    bf8s b3 = *(const bf8s*)(Wrow + (size_t)48*K + k0);
    acc0 = __builtin_amdgcn_mfma_f32_16x16x32_bf16(a, b0, acc0, 0, 0, 0);
    acc1 = __builtin_amdgcn_mfma_f32_16x16x32_bf16(a, b1, acc1, 0, 0, 0);
    acc2 = __builtin_amdgcn_mfma_f32_16x16x32_bf16(a, b2, acc2, 0, 0, 0);
    acc3 = __builtin_amdgcn_mfma_f32_16x16x32_bf16(a, b3, acc3, 0, 0, 0);
  }

  f4 accs[4] = {acc0, acc1, acc2, acc3};
  #pragma unroll
  for (int nt = 0; nt < 4; nt++){
    int n = tile_n + nt*16 + l15;
    float bs = bias[n];
    #pragma unroll
    for (int r = 0; r < 4; r++){
      int m = tile_m + wv*16 + q*4 + r;   // local row within this launch
      float v = accs[nt][r] + bs;
      if (epi == 1){
        if (n < 256) v *= 0.17677669529663689f;
        ((bft*)Cv)[(size_t)m*N + n] = __float2bfloat16(v);
      } else if (epi == 2){
        v = 0.5f*v*(1.f + erff(v*0.70710678118654752f));
        ((bft*)Cv)[(size_t)m*N + n] = __float2bfloat16(v);
      } else if (epi == 3){
        ((float*)Cv)[(size_t)m*N + n] = res[(size_t)m*N + n] + gate[n]*v;
      } else if (epi == 4){
        float s = bn_w[n] * rsqrtf(bn_v[n] + EPS);
        ((float*)Cv)[(size_t)m*N + n] = (v - bn_m[n])*s + bn_b[n];
      } else if (epi == 5){
        float s = bn_w[n] * rsqrtf(bn_v[n] + EPS);
        float o = fmaxf((v - bn_m[n])*s + bn_b[n], 0.f);
        ((bft*)Cv)[(size_t)(t0 + m)*N + n] = __float2bfloat16(o);
      } else { // epi == 6
        if (n < Npost){
          float s = bn_w[n] * rsqrtf(bn_v[n] + EPS);
          float o = fmaxf((v - bn_m[n])*s + bn_b[n], 0.f);
          int tok = t0 + m;
          int xx = tok % WW; int yy = (tok / WW) % HH; int bb = tok / (WW*HH);
          ((float*)Cv)[(((size_t)bb*Npost + n)*HH + yy)*WW + xx] = o;
        }
      }
    }
  }
}

// ---- neighborhood attention: bf16 qkv in, bf16 out ----
__global__ __launch_bounds__(256)
void k_attn(const bft* __restrict__ qkv, const float* __restrict__ rpb,
            bft* __restrict__ o, int Hh, int Ww, int d)
{
  int t = blockIdx.x;
  int j = t % Ww; int i = (t / Ww) % Hh;
  int base = (t / (Ww*Hh)) * Hh * Ww;
  int head = threadIdx.x >> 5;
  int c = threadIdx.x & 31;
  float qv = __bfloat162float(qkv[(size_t)t*768 + head*32 + c]); // pre-scaled
  int is = win_start(i, Hh, d), js = win_start(j, Ww, d);
  int bi = pb_start(i, Hh, d), bj = pb_start(j, Ww, d);
  float logits[25];
  int tns[25];
  #pragma unroll
  for (int x = 0; x < 5; x++){
    int ii = is + x*d;
    #pragma unroll
    for (int y = 0; y < 5; y++){
      int jj = js + y*d;
      int tn = base + ii*Ww + jj;
      tns[x*5+y] = tn;
      float kv = __bfloat162float(qkv[(size_t)tn*768 + 256 + head*32 + c]);
      float p = qv * kv;
      #pragma unroll
      for (int m = 16; m >= 1; m >>= 1) p += __shfl_xor(p, m, 32);
      p += rpb[head*81 + (bi + x)*9 + (bj + y)];
      logits[x*5+y] = p;
    }
  }
  float mx = logits[0];
  #pragma unroll
  for (int p = 1; p < 25; p++) mx = fmaxf(mx, logits[p]);
  float ssum = 0.f;
  #pragma unroll
  for (int p = 0; p < 25; p++){ float e = expf(logits[p] - mx); logits[p] = e; ssum += e; }
  float inv = 1.f / ssum;
  float acc = 0.f;
  #pragma unroll
  for (int p = 0; p < 25; p++)
    acc += logits[p] * __bfloat162float(qkv[(size_t)tns[p]*768 + 512 + head*32 + c]);
  o[(size_t)t*256 + head*32 + c] = __float2bfloat16(acc * inv);
}

// ---- fuse-cat: A[t][0..255]=feat(NCHW f32), A[t][256..511]=bilinear(Xprev) ----
__global__ __launch_bounds__(256)
void k_fusecat(const float* __restrict__ feat, const float* __restrict__ xprev,
               bft* __restrict__ out, int h, int w, int H2, int W2)
{
  int t = blockIdx.x; int c = threadIdx.x;
  int x = t % W2; int y = (t / W2) % H2; int b = t / (W2*H2);
  out[(size_t)t*512 + c] = __float2bfloat16(feat[(((size_t)b*256 + c)*H2 + y)*W2 + x]);
  float fy = (float)y * (float)(h-1) / (float)(H2-1);
  float fx = (float)x * (float)(w-1) / (float)(W2-1);
  int y0 = (int)floorf(fy); int y1 = min(y0+1, h-1); float wy = fy - (float)y0;
  int x0 = (int)floorf(fx); int x1 = min(x0+1, w-1); float wx = fx - (float)x0;
  const float* basep = xprev + (size_t)b*h*w*256;
  float a  = basep[((size_t)y0*w + x0)*256 + c];
  float bb = basep[((size_t)y0*w + x1)*256 + c];
  float cc = basep[((size_t)y1*w + x0)*256 + c];
  float e  = basep[((size_t)y1*w + x1)*256 + c];
  float u = a*(1.f-wy)*(1.f-wx) + bb*(1.f-wy)*wx + cc*wy*(1.f-wx) + e*wy*wx;
  out[(size_t)t*512 + 256 + c] = __float2bfloat16(u);
}

// ---- im2col: token patch rows (K=2304) bf16; input f32 or bf16 NHWC ----
__global__ __launch_bounds__(256)
void k_im2col(const void* __restrict__ in, int in_is_bf16, bft* __restrict__ out,
              int H, int W, int t0)
{
  int tl = blockIdx.x; int c = threadIdx.x;
  int tok = t0 + tl;
  int x = tok % W; int y = (tok / W) % H; int b = tok / (W*H);
  #pragma unroll
  for (int tap = 0; tap < 9; tap++){
    int ky = tap/3 - 1, kx = tap%3 - 1;
    int yy = y + ky, xx = x + kx;
    bft v;
    if (yy >= 0 && yy < H && xx >= 0 && xx < W){
      size_t idx = (((size_t)b*H + yy)*W + xx)*256 + c;
      v = in_is_bf16 ? ((const bft*)in)[idx] : __float2bfloat16(((const float*)in)[idx]);
    } else v = __float2bfloat16(0.f);
    out[(size_t)tl*2304 + tap*256 + c] = v;
  }
}

extern "C" void kernel_launch(void* const* d_in, const int* in_sizes, int n_in,
                              void* d_out, int out_size, void* d_ws, size_t ws_size,
                              hipStream_t stream)
{
  (void)in_sizes; (void)n_in; (void)out_size; (void)ws_size;
  const float* x0     = (const float*)d_in[0];
  const float* x1     = (const float*)d_in[1];
  const float* x2     = (const float*)d_in[2];
  const float* x3     = (const float*)d_in[3];
  const float* ln1_w  = (const float*)d_in[4];
  const float* ln1_b  = (const float*)d_in[5];
  const float* qkv_w  = (const float*)d_in[6];
  const float* qkv_b  = (const float*)d_in[7];
  const float* rpb    = (const float*)d_in[8];
  const float* proj_w = (const float*)d_in[9];
  const float* proj_b = (const float*)d_in[10];
  const float* ln2_w  = (const float*)d_in[11];
  const float* ln2_b  = (const float*)d_in[12];
  const float* fc1_w  = (const float*)d_in[13];
  const float* fc1_b  = (const float*)d_in[14];
  const float* fc2_w  = (const float*)d_in[15];
  const float* fc2_b  = (const float*)d_in[16];
  const float* g1     = (const float*)d_in[17];
  const float* g2     = (const float*)d_in[18];
  const float* fuse_w = (const float*)d_in[19];
  const float* fuse_b = (const float*)d_in[20];
  const float* fbn_w  = (const float*)d_in[21];
  const float* fbn_b  = (const float*)d_in[22];
  const float* fbn_m  = (const float*)d_in[23];
  const float* fbn_v  = (const float*)d_in[24];
  const float* lc1_w  = (const float*)d_in[25];
  const float* lc1_b  = (const float*)d_in[26];
  const float* lbn1_w = (const float*)d_in[27];
  const float* lbn1_b = (const float*)d_in[28];
  const float* lbn1_m = (const float*)d_in[29];
  const float* lbn1_v = (const float*)d_in[30];
  const float* lc2_w  = (const float*)d_in[31];
  const float* lc2_b  = (const float*)d_in[32];
  const float* lbn2_w = (const float*)d_in[33];
  const float* lbn2_b = (const float*)d_in[34];
  const float* lbn2_m = (const float*)d_in[35];
  const float* lbn2_v = (const float*)d_in[36];

  // ---- workspace layout (bytes) ----
  char* ws = (char*)d_ws;
  float* X  = (float*)ws;                      // 12288*256 f32   = 12,582,912 B
  bft*   B1 = (bft*)(ws + 12582912);           // 12288*256 bf16  =  6,291,456 B
  bft*   B2 = (bft*)(ws + 18874368);           // 12288*1024 bf16 = 25,165,824 B
  bft*   IM = (bft*)(ws + 44040192);           // max(3072*2304, 12288*512) bf16 = 14,155,776 B
  bft*   WL = (bft*)(ws + 58195968);           // 786432 bf16     =  1,572,864 B

  // per-layer weight slice sizes (elements)
  const int NQKV = 196608, NPROJ = 65536, NFC1 = 262144, NFC2 = 262144;
  bft* wQKV = WL;
  bft* wPROJ = WL + NQKV;
  bft* wFC1  = WL + NQKV + NPROJ;
  bft* wFC2  = WL + NQKV + NPROJ + NFC1;

  auto gemm = [&](const bft* A, const bft* W, const float* bias, void* C,
                  int Mloc, int N, int K, int epi, int t0, int Npost,
                  const float* res, const float* gate,
                  const float* bw, const float* bb, const float* bm, const float* bv,
                  int HH, int WW){
    dim3 g(N/64, Mloc/64);
    k_gemm<<<g, 256, 0, stream>>>(A, W, bias, C, N, K, epi, t0, Npost,
                                  res, gate, bw, bb, bm, bv, HH, WW);
  };

  auto nat = [&](int l, int d, int Hh, int Ww){
    int T = 4*Hh*Ww;
    // convert this layer's 4 weight tensors to bf16 in one launch
    k_cvt4<<<768, 256, 0, stream>>>(qkv_w + (size_t)l*NQKV, NQKV,
                                    proj_w + (size_t)l*NPROJ, NPROJ,
                                    fc1_w + (size_t)l*NFC1, NFC1,
                                    fc2_w + (size_t)l*NFC2, NFC2, WL);
    k_ln<<<T, 256, 0, stream>>>(X, ln1_w + l*256, ln1_b + l*256, B1);
    gemm(B1, wQKV, qkv_b + l*768, B2, T, 768, 256, 1, 0, 0,
         nullptr, nullptr, nullptr, nullptr, nullptr, nullptr, 0, 0);
    k_attn<<<T, 256, 0, stream>>>(B2, rpb + l*648, B1, Hh, Ww, d);
    gemm(B1, wPROJ, proj_b + l*256, X, T, 256, 256, 3, 0, 0,
         X, g1 + l*256, nullptr, nullptr, nullptr, nullptr, 0, 0);
    k_ln<<<T, 256, 0, stream>>>(X, ln2_w + l*256, ln2_b + l*256, B1);
    gemm(B1, wFC1, fc1_b + l*1024, B2, T, 1024, 256, 2, 0, 0,
         nullptr, nullptr, nullptr, nullptr, nullptr, nullptr, 0, 0);
    gemm(B2, wFC2, fc2_b + l*256, X, T, 256, 1024, 3, 0, 0,
         X, g2 + l*256, nullptr, nullptr, nullptr, nullptr, 0, 0);
  };

  auto fuse = [&](int i, const float* feat, int h, int w, int H2, int W2){
    int Tn = 4*H2*W2;
    k_cvt4<<<512, 256, 0, stream>>>(fuse_w + (size_t)i*131072, 131072,
                                    nullptr, 0, nullptr, 0, nullptr, 0, WL);
    k_fusecat<<<Tn, 256, 0, stream>>>(feat, X, IM, h, w, H2, W2);
    gemm(IM, WL, fuse_b + i*256, X, Tn, 256, 512, 4, 0, 0,
         nullptr, nullptr, fbn_w + i*256, fbn_b + i*256, fbn_m + i*256, fbn_v + i*256, 0, 0);
  };

  // level 3: 8x6
  k_nchw2nhwc<<<4*8*6, 256, 0, stream>>>(x3, X, 8, 6);
  nat(0, 1, 8, 6);
  nat(1, 1, 8, 6);
  fuse(0, x2, 8, 6, 16, 12);
  // level 2: 16x12
  nat(2, 2, 16, 12);
  nat(3, 2, 16, 12);
  fuse(1, x1, 16, 12, 32, 24);
  // level 1: 32x24
  nat(4, 4, 32, 24);
  nat(5, 4, 32, 24);
  fuse(2, x0, 32, 24, 64, 48);
  // level 0: 64x48
  nat(6, 8, 64, 48);
  nat(7, 8, 64, 48);

  // ---- conv1: im2col (per-batch chunks) + MFMA GEMM, BN+ReLU -> B1 (bf16) ----
  k_repack<<<256, 256, 0, stream>>>(lc1_w, WL, 256);
  for (int b = 0; b < 4; b++){
    k_im2col<<<3072, 256, 0, stream>>>(X, 0, IM, 64, 48, b*3072);
    gemm(IM, WL, lc1_b, B1, 3072, 256, 2304, 5, b*3072, 0,
         nullptr, nullptr, lbn1_w, lbn1_b, lbn1_m, lbn1_v, 0, 0);
  }
  // ---- conv2: im2col from B1 (bf16) + GEMM (N padded to 64), -> d_out NCHW ----
  k_repack<<<64, 256, 0, stream>>>(lc2_w, WL, 17);
  for (int b = 0; b < 4; b++){
    k_im2col<<<3072, 256, 0, stream>>>(B1, 1, IM, 64, 48, b*3072);
    gemm(IM, WL, lc2_b, d_out, 3072, 64, 2304, 6, b*3072, 17,
         nullptr, nullptr, lbn2_w, lbn2_b, lbn2_m, lbn2_v, 64, 48);
  }
}

// Round 4
// 1692.342 us; speedup vs baseline: 4.4242x; 1.0672x over previous
//
#include <hip/hip_runtime.h>
#include <hip/hip_bf16.h>

typedef __hip_bfloat16 bft;
typedef short bf8s __attribute__((ext_vector_type(8)));   // 8 bf16 (4 VGPRs)
typedef float f4 __attribute__((ext_vector_type(4)));

#define KW 5
#define NSW 2
#define EPS 1e-5f

__device__ __forceinline__ float bs2f(short s){
  union { unsigned u; float f; } v; v.u = ((unsigned)(unsigned short)s) << 16; return v.f;
}

__device__ __forceinline__ int win_start(int i, int L, int d){
  if (d <= 1){
    int s = i - NSW; if (s < 0) s = 0;
    if (i + NSW >= L) s += L - i - NSW - 1;
    return s;
  }
  int ni = i - NSW*d;
  if (ni < 0) return i % d;
  if (i + NSW*d >= L){
    int imodd = i % d;
    int a = (L / d) * d;
    int b = L - a;
    if (imodd < b) return L - b + imodd - 2*NSW*d;
    return a + imodd - KW*d;
  }
  return ni;
}
__device__ __forceinline__ int pb_start(int i, int L, int d){
  if (d <= 1){
    int s = NSW;
    if (i < NSW) s += NSW - i;
    if (i + NSW >= L) s += L - i - 1 - NSW;
    return s;
  }
  if (i - NSW*d < 0) return KW - 1 - i/d;
  if (i + NSW*d >= L) return (L - i - 1)/d;
  return NSW;
}

// ---- upfront: all 8 NAT layers' weights fp32 -> bf16, layer-contiguous ----
__global__ __launch_bounds__(256)
void k_cvt_nat(const float* __restrict__ qkv_w, const float* __restrict__ proj_w,
               const float* __restrict__ fc1_w, const float* __restrict__ fc2_w,
               bft* __restrict__ dst)
{
  for (int i = blockIdx.x*256 + threadIdx.x; i < 8*786432; i += gridDim.x*256){
    int l = i / 786432;
    int off = i - l*786432;
    float v;
    if (off < 196608) v = qkv_w[(size_t)l*196608 + off];
    else if (off < 262144) v = proj_w[(size_t)l*65536 + (off - 196608)];
    else if (off < 524288) v = fc1_w[(size_t)l*262144 + (off - 262144)];
    else v = fc2_w[(size_t)l*262144 + (off - 524288)];
    dst[i] = __float2bfloat16(v);
  }
}

// ---- fp32 -> bf16 convert, up to 4 source segments ----
__global__ __launch_bounds__(256)
void k_cvt4(const float* __restrict__ s0, int n0, const float* __restrict__ s1, int n1,
            const float* __restrict__ s2, int n2, const float* __restrict__ s3, int n3,
            bft* __restrict__ dst)
{
  int total = n0 + n1 + n2 + n3;
  for (int i = blockIdx.x*256 + threadIdx.x; i < total; i += gridDim.x*256){
    float v;
    int j = i;
    if (j < n0) v = s0[j];
    else { j -= n0;
      if (j < n1) v = s1[j];
      else { j -= n1;
        if (j < n2) v = s2[j];
        else v = s3[j - n2];
      }
    }
    dst[i] = __float2bfloat16(v);
  }
}

// ---- conv weight repack: OIHW fp32 -> [o][tap*256+c] bf16 (o padded) ----
__global__ __launch_bounds__(256)
void k_repack(const float* __restrict__ in, bft* __restrict__ out, int O_in)
{
  int o = blockIdx.x, c = threadIdx.x;
  #pragma unroll
  for (int tap = 0; tap < 9; tap++){
    float v = (o < O_in) ? in[((size_t)(o*256 + c))*9 + tap] : 0.f;
    out[(size_t)o*2304 + tap*256 + c] = __float2bfloat16(v);
  }
}

// ---- NCHW -> NHWC (f32) ----
__global__ __launch_bounds__(256)
void k_nchw2nhwc(const float* __restrict__ in, float* __restrict__ out,
                 int H, int W){
  int t = blockIdx.x; int c = threadIdx.x;
  int x = t % W; int y = (t / W) % H; int b = t / (W*H);
  out[(size_t)t*256 + c] = in[(((size_t)b*256 + c)*H + y)*W + x];
}

// ---- LayerNorm (C=256), one block per token; fp32 in, bf16 out ----
__global__ __launch_bounds__(256)
void k_ln(const float* __restrict__ x, const float* __restrict__ w,
          const float* __restrict__ b, bft* __restrict__ out)
{
  __shared__ float red[4];
  __shared__ float stats[2];
  int t = blockIdx.x, c = threadIdx.x;
  float v = x[(size_t)t*256 + c];
  float s = v;
  #pragma unroll
  for (int m = 32; m >= 1; m >>= 1) s += __shfl_xor(s, m, 64);
  int wave = c >> 6;
  if ((c & 63) == 0) red[wave] = s;
  __syncthreads();
  if (c == 0) stats[0] = (red[0]+red[1]+red[2]+red[3]) * (1.f/256.f);
  __syncthreads();
  float mean = stats[0];
  float dd = v - mean;
  float s2 = dd*dd;
  #pragma unroll
  for (int m = 32; m >= 1; m >>= 1) s2 += __shfl_xor(s2, m, 64);
  if ((c & 63) == 0) red[wave] = s2;
  __syncthreads();
  if (c == 0) stats[1] = (red[0]+red[1]+red[2]+red[3]) * (1.f/256.f);
  __syncthreads();
  float var = stats[1];
  out[(size_t)t*256 + c] = __float2bfloat16(dd * rsqrtf(var + EPS) * w[c] + b[c]);
}

// ---- MFMA bf16 GEMM: C[m,n] = epi( sum_k A[m,k]*W[n,k] + bias[n] ) ----
// epi: 1 qkv-scale(n<256)->bf16; 2 gelu->bf16; 3 res+gate->f32;
//      4 fuse-BN->f32; 5 conv-BN+ReLU->bf16; 6 conv-BN+ReLU->f32 NCHW (n<Npost)
__global__ __launch_bounds__(256)
void k_gemm(const bft* __restrict__ A, const bft* __restrict__ W,
            const float* __restrict__ bias, void* __restrict__ Cv,
            int N, int K, int epi, int t0, int Npost,
            const float* __restrict__ res, const float* __restrict__ gate,
            const float* __restrict__ bn_w, const float* __restrict__ bn_b,
            const float* __restrict__ bn_m, const float* __restrict__ bn_v,
            int HH, int WW)
{
  int tile_n = blockIdx.x * 64;
  int tile_m = blockIdx.y * 64;
  int tid = threadIdx.x;
  int wv   = tid >> 6;
  int lane = tid & 63;
  int q    = lane >> 4;
  int l15  = lane & 15;

  const bft* Arow  = A + (size_t)(tile_m + wv*16 + l15) * K + q*8;
  const bft* Wrow  = W + (size_t)(tile_n + l15) * K + q*8;

  f4 acc0 = {0.f,0.f,0.f,0.f};
  f4 acc1 = acc0, acc2 = acc0, acc3 = acc0;

  for (int k0 = 0; k0 < K; k0 += 32){
    bf8s a  = *(const bf8s*)(Arow + k0);
    bf8s b0 = *(const bf8s*)(Wrow + k0);
    bf8s b1 = *(const bf8s*)(Wrow + (size_t)16*K + k0);
    bf8s b2 = *(const bf8s*)(Wrow + (size_t)32*K + k0);
    bf8s b3 = *(const bf8s*)(Wrow + (size_t)48*K + k0);
    acc0 = __builtin_amdgcn_mfma_f32_16x16x32_bf16(a, b0, acc0, 0, 0, 0);
    acc1 = __builtin_amdgcn_mfma_f32_16x16x32_bf16(a, b1, acc1, 0, 0, 0);
    acc2 = __builtin_amdgcn_mfma_f32_16x16x32_bf16(a, b2, acc2, 0, 0, 0);
    acc3 = __builtin_amdgcn_mfma_f32_16x16x32_bf16(a, b3, acc3, 0, 0, 0);
  }

  f4 accs[4] = {acc0, acc1, acc2, acc3};
  #pragma unroll
  for (int nt = 0; nt < 4; nt++){
    int n = tile_n + nt*16 + l15;
    float bs = bias[n];
    #pragma unroll
    for (int r = 0; r < 4; r++){
      int m = tile_m + wv*16 + q*4 + r;
      float v = accs[nt][r] + bs;
      if (epi == 1){
        if (n < 256) v *= 0.17677669529663689f;
        ((bft*)Cv)[(size_t)m*N + n] = __float2bfloat16(v);
      } else if (epi == 2){
        v = 0.5f*v*(1.f + erff(v*0.70710678118654752f));
        ((bft*)Cv)[(size_t)m*N + n] = __float2bfloat16(v);
      } else if (epi == 3){
        ((float*)Cv)[(size_t)m*N + n] = res[(size_t)m*N + n] + gate[n]*v;
      } else if (epi == 4){
        float s = bn_w[n] * rsqrtf(bn_v[n] + EPS);
        ((float*)Cv)[(size_t)m*N + n] = (v - bn_m[n])*s + bn_b[n];
      } else if (epi == 5){
        float s = bn_w[n] * rsqrtf(bn_v[n] + EPS);
        float o = fmaxf((v - bn_m[n])*s + bn_b[n], 0.f);
        ((bft*)Cv)[(size_t)(t0 + m)*N + n] = __float2bfloat16(o);
      } else { // epi == 6
        if (n < Npost){
          float s = bn_w[n] * rsqrtf(bn_v[n] + EPS);
          float o = fmaxf((v - bn_m[n])*s + bn_b[n], 0.f);
          int tok = t0 + m;
          int xx = tok % WW; int yy = (tok / WW) % HH; int bb = tok / (WW*HH);
          ((float*)Cv)[(((size_t)bb*Npost + n)*HH + yy)*WW + xx] = o;
        }
      }
    }
  }
}

// ---- neighborhood attention: one THREAD per (token, head); no shuffles ----
__global__ __launch_bounds__(256)
void k_attn(const bft* __restrict__ qkv, const float* __restrict__ rpb,
            bft* __restrict__ o, int Hh, int Ww, int d)
{
  int gid  = blockIdx.x*256 + threadIdx.x;
  int head = gid & 7;
  int t    = gid >> 3;
  int j = t % Ww; int i = (t / Ww) % Hh;
  int base = (t / (Ww*Hh)) * Hh * Ww;

  // q: 32 fp32 regs (pre-scaled by qkv epilogue)
  const bft* qp = qkv + (size_t)t*768 + head*32;
  float q[32];
  #pragma unroll
  for (int u = 0; u < 4; u++){
    bf8s qv = *(const bf8s*)(qp + u*8);
    #pragma unroll
    for (int e = 0; e < 8; e++) q[u*8+e] = bs2f(qv[e]);
  }

  int is = win_start(i, Hh, d), js = win_start(j, Ww, d);
  int bi = pb_start(i, Hh, d), bj = pb_start(j, Ww, d);

  float logits[25];
  int tns[25];
  #pragma unroll
  for (int x = 0; x < 5; x++){
    int rowb = base + (is + x*d)*Ww;
    #pragma unroll
    for (int y = 0; y < 5; y++){
      int tn = rowb + js + y*d;
      tns[x*5+y] = tn;
      const bft* kp = qkv + (size_t)tn*768 + 256 + head*32;
      float s = 0.f;
      #pragma unroll
      for (int u = 0; u < 4; u++){
        bf8s kv = *(const bf8s*)(kp + u*8);
        #pragma unroll
        for (int e = 0; e < 8; e++) s += q[u*8+e] * bs2f(kv[e]);
      }
      logits[x*5+y] = s + rpb[head*81 + (bi + x)*9 + (bj + y)];
    }
  }

  float mx = logits[0];
  #pragma unroll
  for (int p = 1; p < 25; p++) mx = fmaxf(mx, logits[p]);
  float ssum = 0.f;
  #pragma unroll
  for (int p = 0; p < 25; p++){ float e = __expf(logits[p] - mx); logits[p] = e; ssum += e; }
  float inv = 1.f / ssum;

  float acc[32];
  #pragma unroll
  for (int e = 0; e < 32; e++) acc[e] = 0.f;
  #pragma unroll
  for (int p = 0; p < 25; p++){
    float wgt = logits[p] * inv;
    const bft* vp = qkv + (size_t)tns[p]*768 + 512 + head*32;
    #pragma unroll
    for (int u = 0; u < 4; u++){
      bf8s vv = *(const bf8s*)(vp + u*8);
      #pragma unroll
      for (int e = 0; e < 8; e++) acc[u*8+e] += wgt * bs2f(vv[e]);
    }
  }

  bft* op = o + (size_t)t*256 + head*32;
  #pragma unroll
  for (int u = 0; u < 4; u++){
    bf8s ov;
    #pragma unroll
    for (int e = 0; e < 8; e++){
      bft h = __float2bfloat16(acc[u*8+e]);
      union { bft b; short s; } cv; cv.b = h;
      ov[e] = cv.s;
    }
    *(bf8s*)(op + u*8) = ov;
  }
}

// ---- fuse-cat: A[t][0..255]=feat(NCHW f32), A[t][256..511]=bilinear(Xprev) ----
__global__ __launch_bounds__(256)
void k_fusecat(const float* __restrict__ feat, const float* __restrict__ xprev,
               bft* __restrict__ out, int h, int w, int H2, int W2)
{
  int t = blockIdx.x; int c = threadIdx.x;
  int x = t % W2; int y = (t / W2) % H2; int b = t / (W2*H2);
  out[(size_t)t*512 + c] = __float2bfloat16(feat[(((size_t)b*256 + c)*H2 + y)*W2 + x]);
  float fy = (float)y * (float)(h-1) / (float)(H2-1);
  float fx = (float)x * (float)(w-1) / (float)(W2-1);
  int y0 = (int)floorf(fy); int y1 = min(y0+1, h-1); float wy = fy - (float)y0;
  int x0 = (int)floorf(fx); int x1 = min(x0+1, w-1); float wx = fx - (float)x0;
  const float* basep = xprev + (size_t)b*h*w*256;
  float a  = basep[((size_t)y0*w + x0)*256 + c];
  float bb = basep[((size_t)y0*w + x1)*256 + c];
  float cc = basep[((size_t)y1*w + x0)*256 + c];
  float e  = basep[((size_t)y1*w + x1)*256 + c];
  float u = a*(1.f-wy)*(1.f-wx) + bb*(1.f-wy)*wx + cc*wy*(1.f-wx) + e*wy*wx;
  out[(size_t)t*512 + 256 + c] = __float2bfloat16(u);
}

// ---- im2col: token patch rows (K=2304) bf16; input f32 or bf16 NHWC ----
__global__ __launch_bounds__(256)
void k_im2col(const void* __restrict__ in, int in_is_bf16, bft* __restrict__ out,
              int H, int W, int t0)
{
  int tl = blockIdx.x; int c = threadIdx.x;
  int tok = t0 + tl;
  int x = tok % W; int y = (tok / W) % H; int b = tok / (W*H);
  #pragma unroll
  for (int tap = 0; tap < 9; tap++){
    int ky = tap/3 - 1, kx = tap%3 - 1;
    int yy = y + ky, xx = x + kx;
    bft v;
    if (yy >= 0 && yy < H && xx >= 0 && xx < W){
      size_t idx = (((size_t)b*H + yy)*W + xx)*256 + c;
      v = in_is_bf16 ? ((const bft*)in)[idx] : __float2bfloat16(((const float*)in)[idx]);
    } else v = __float2bfloat16(0.f);
    out[(size_t)tl*2304 + tap*256 + c] = v;
  }
}

extern "C" void kernel_launch(void* const* d_in, const int* in_sizes, int n_in,
                              void* d_out, int out_size, void* d_ws, size_t ws_size,
                              hipStream_t stream)
{
  (void)in_sizes; (void)n_in; (void)out_size; (void)ws_size;
  const float* x0     = (const float*)d_in[0];
  const float* x1     = (const float*)d_in[1];
  const float* x2     = (const float*)d_in[2];
  const float* x3     = (const float*)d_in[3];
  const float* ln1_w  = (const float*)d_in[4];
  const float* ln1_b  = (const float*)d_in[5];
  const float* qkv_w  = (const float*)d_in[6];
  const float* qkv_b  = (const float*)d_in[7];
  const float* rpb    = (const float*)d_in[8];
  const float* proj_w = (const float*)d_in[9];
  const float* proj_b = (const float*)d_in[10];
  const float* ln2_w  = (const float*)d_in[11];
  const float* ln2_b  = (const float*)d_in[12];
  const float* fc1_w  = (const float*)d_in[13];
  const float* fc1_b  = (const float*)d_in[14];
  const float* fc2_w  = (const float*)d_in[15];
  const float* fc2_b  = (const float*)d_in[16];
  const float* g1     = (const float*)d_in[17];
  const float* g2     = (const float*)d_in[18];
  const float* fuse_w = (const float*)d_in[19];
  const float* fuse_b = (const float*)d_in[20];
  const float* fbn_w  = (const float*)d_in[21];
  const float* fbn_b  = (const float*)d_in[22];
  const float* fbn_m  = (const float*)d_in[23];
  const float* fbn_v  = (const float*)d_in[24];
  const float* lc1_w  = (const float*)d_in[25];
  const float* lc1_b  = (const float*)d_in[26];
  const float* lbn1_w = (const float*)d_in[27];
  const float* lbn1_b = (const float*)d_in[28];
  const float* lbn1_m = (const float*)d_in[29];
  const float* lbn1_v = (const float*)d_in[30];
  const float* lc2_w  = (const float*)d_in[31];
  const float* lc2_b  = (const float*)d_in[32];
  const float* lbn2_w = (const float*)d_in[33];
  const float* lbn2_b = (const float*)d_in[34];
  const float* lbn2_m = (const float*)d_in[35];
  const float* lbn2_v = (const float*)d_in[36];

  // ---- workspace layout (bytes), total 58,884,096 ----
  char* ws = (char*)d_ws;
  float* X  = (float*)ws;                      // 12288*256 f32   = 12,582,912
  bft*   B1 = (bft*)(ws + 12582912);           // 12288*256 bf16  =  6,291,456
  bft*   B2 = (bft*)(ws + 18874368);           // 12288*1024 bf16 = 25,165,824
  bft*   IM = B2;                              // aliases B2 (liveness-disjoint)
  bft*   WB = (bft*)(ws + 44040192);           // weights: 7,421,952 bf16

  bft* W_NAT  = WB;                            // 8 * 786432
  bft* W_FUSE = WB + 6291456;                  // 3 * 131072
  bft* W_C1   = WB + 6684672;                  // 256*2304
  bft* W_C2   = WB + 7274496;                  // 64*2304

  // upfront weight conversion (4 launches)
  k_cvt_nat<<<2048, 256, 0, stream>>>(qkv_w, proj_w, fc1_w, fc2_w, W_NAT);
  k_cvt4<<<512, 256, 0, stream>>>(fuse_w, 393216, nullptr, 0, nullptr, 0, nullptr, 0, W_FUSE);
  k_repack<<<256, 256, 0, stream>>>(lc1_w, W_C1, 256);
  k_repack<<<64, 256, 0, stream>>>(lc2_w, W_C2, 17);

  auto gemm = [&](const bft* A, const bft* W, const float* bias, void* C,
                  int Mloc, int N, int K, int epi, int t0, int Npost,
                  const float* res, const float* gate,
                  const float* bw, const float* bb, const float* bm, const float* bv,
                  int HH, int WW){
    dim3 g(N/64, Mloc/64);
    k_gemm<<<g, 256, 0, stream>>>(A, W, bias, C, N, K, epi, t0, Npost,
                                  res, gate, bw, bb, bm, bv, HH, WW);
  };

  auto nat = [&](int l, int d, int Hh, int Ww){
    int T = 4*Hh*Ww;
    bft* wQKV  = W_NAT + (size_t)l*786432;
    bft* wPROJ = wQKV + 196608;
    bft* wFC1  = wQKV + 262144;
    bft* wFC2  = wQKV + 524288;
    k_ln<<<T, 256, 0, stream>>>(X, ln1_w + l*256, ln1_b + l*256, B1);
    gemm(B1, wQKV, qkv_b + l*768, B2, T, 768, 256, 1, 0, 0,
         nullptr, nullptr, nullptr, nullptr, nullptr, nullptr, 0, 0);
    k_attn<<<T*8/256, 256, 0, stream>>>(B2, rpb + l*648, B1, Hh, Ww, d);
    gemm(B1, wPROJ, proj_b + l*256, X, T, 256, 256, 3, 0, 0,
         X, g1 + l*256, nullptr, nullptr, nullptr, nullptr, 0, 0);
    k_ln<<<T, 256, 0, stream>>>(X, ln2_w + l*256, ln2_b + l*256, B1);
    gemm(B1, wFC1, fc1_b + l*1024, B2, T, 1024, 256, 2, 0, 0,
         nullptr, nullptr, nullptr, nullptr, nullptr, nullptr, 0, 0);
    gemm(B2, wFC2, fc2_b + l*256, X, T, 256, 1024, 3, 0, 0,
         X, g2 + l*256, nullptr, nullptr, nullptr, nullptr, 0, 0);
  };

  auto fuse = [&](int i, const float* feat, int h, int w, int H2, int W2){
    int Tn = 4*H2*W2;
    k_fusecat<<<Tn, 256, 0, stream>>>(feat, X, IM, h, w, H2, W2);
    gemm(IM, W_FUSE + (size_t)i*131072, fuse_b + i*256, X, Tn, 256, 512, 4, 0, 0,
         nullptr, nullptr, fbn_w + i*256, fbn_b + i*256, fbn_m + i*256, fbn_v + i*256, 0, 0);
  };

  // level 3: 8x6
  k_nchw2nhwc<<<4*8*6, 256, 0, stream>>>(x3, X, 8, 6);
  nat(0, 1, 8, 6);
  nat(1, 1, 8, 6);
  fuse(0, x2, 8, 6, 16, 12);
  // level 2: 16x12
  nat(2, 2, 16, 12);
  nat(3, 2, 16, 12);
  fuse(1, x1, 16, 12, 32, 24);
  // level 1: 32x24
  nat(4, 4, 32, 24);
  nat(5, 4, 32, 24);
  fuse(2, x0, 32, 24, 64, 48);
  // level 0: 64x48
  nat(6, 8, 64, 48);
  nat(7, 8, 64, 48);

  // ---- conv1: im2col (per-batch chunks) + MFMA GEMM, BN+ReLU -> B1 (bf16) ----
  for (int b = 0; b < 4; b++){
    k_im2col<<<3072, 256, 0, stream>>>(X, 0, IM, 64, 48, b*3072);
    gemm(IM, W_C1, lc1_b, B1, 3072, 256, 2304, 5, b*3072, 0,
         nullptr, nullptr, lbn1_w, lbn1_b, lbn1_m, lbn1_v, 0, 0);
  }
  // ---- conv2: im2col from B1 (bf16) + GEMM (N padded to 64) -> d_out NCHW ----
  for (int b = 0; b < 4; b++){
    k_im2col<<<3072, 256, 0, stream>>>(B1, 1, IM, 64, 48, b*3072);
    gemm(IM, W_C2, lc2_b, d_out, 3072, 64, 2304, 6, b*3072, 17,
         nullptr, nullptr, lbn2_w, lbn2_b, lbn2_m, lbn2_v, 64, 48);
  }
}